// Round 6
// baseline (1031.445 us; speedup 1.0000x reference)
//
#include <hip/hip_runtime.h>
#include <hip/hip_bf16.h>
#include <cstdint>

#define NU 50000
#define NI 50000
#define NN 50000
#define EE 800000
#define DIN 256
#define NH 4
#define DOUT 32
#define HD 128       // NH*DOUT
#define WC 176       // padded GEMM cols: [hs 128 | loop 32 | el 4 | er 4 | pad 8]
#define NCH 196      // ceil(NN/256)
#define NB 196       // dst buckets per relation (dst>>8)
#define BCAP 6144    // bucket capacity (mean 4096, sigma 64 -> 32 sigma slack)

typedef __attribute__((ext_vector_type(8))) short short8;
typedef __attribute__((ext_vector_type(4))) float f32x4;

__device__ __forceinline__ float leakyf(float x){ return x > 0.f ? x : 0.2f*x; }
__device__ __forceinline__ float eluf(float x){ return x > 0.f ? x : expm1f(x); }
__device__ __forceinline__ unsigned short f2bf(float x){
  unsigned u = __float_as_uint(x);
  return (unsigned short)((u + 0x7FFFu + ((u >> 16) & 1u)) >> 16);   // RNE
}
__device__ __forceinline__ float bf2f(unsigned short b){
  return __uint_as_float(((unsigned)b) << 16);
}
__device__ __forceinline__ float bflo(unsigned r){ return __uint_as_float(r << 16); }
__device__ __forceinline__ float bfhi(unsigned r){ return __uint_as_float(r & 0xffff0000u); }
__device__ __forceinline__ unsigned pk2(float x, float y){
  __hip_bfloat162 b = __float22bfloat162_rn(make_float2(x, y));
  union { __hip_bfloat162 b2; unsigned u; } c; c.b2 = b; return c.u;
}

// Wt[c][k] bf16, c<176 (cols 168-175 zero), k<256.
__global__ void pack_wt(const float* __restrict__ fc_a, const float* __restrict__ attn_l_a,
                        const float* __restrict__ fc_b, const float* __restrict__ attn_r_b,
                        const float* __restrict__ loopw, unsigned short* __restrict__ Wt) {
  int t = blockIdx.x*blockDim.x + threadIdx.x;
  if (t >= WC*DIN) return;
  int c = t >> 8, k = t & 255;
  float v = 0.f;
  if (c < HD) v = fc_a[k*HD + c];
  else if (c < HD+DOUT) v = loopw[k*DOUT + (c-HD)];
  else if (c < HD+DOUT+NH) {
    int h = c - (HD+DOUT); float s = 0.f;
    for (int dd = 0; dd < DOUT; ++dd) s += fc_a[k*HD + h*DOUT + dd] * attn_l_a[h*DOUT + dd];
    v = s;
  } else if (c < HD+DOUT+2*NH) {
    int h = c - (HD+DOUT+NH); float s = 0.f;
    for (int dd = 0; dd < DOUT; ++dd) s += fc_b[k*HD + h*DOUT + dd] * attn_r_b[h*DOUT + dd];
    v = s;
  }
  Wt[t] = f2bf(v);
}

// MFMA GEMM: A[M][256] f32 -> (A @ W)[M][176], split-written to hsb/loopb/scb.
__global__ __launch_bounds__(512) void gemm_mfma(const float* __restrict__ A,
                                                 const unsigned short* __restrict__ Wt,
                                                 unsigned short* __restrict__ hsb,
                                                 unsigned short* __restrict__ loopb,
                                                 float* __restrict__ scb, int M) {
  __shared__ __align__(16) unsigned short As[128*40];
  __shared__ __align__(16) unsigned short Ws[176*40];
  int t = threadIdx.x;
  int bm = blockIdx.x * 128;
  int w = t >> 6, l = t & 63;
  int r16 = l & 15, g4 = l >> 4;
  f32x4 acc[11];
  #pragma unroll
  for (int f = 0; f < 11; ++f) acc[f] = (f32x4){0.f,0.f,0.f,0.f};

  for (int k0 = 0; k0 < DIN; k0 += 32) {
    {
      int row = t >> 2, off = (t & 3) * 8;
      int gr = bm + row;
      float4 v0 = make_float4(0.f,0.f,0.f,0.f), v1 = v0;
      if (gr < M) {
        const float* ap = A + (size_t)gr*DIN + k0 + off;
        v0 = *(const float4*)ap;
        v1 = *(const float4*)(ap + 4);
      }
      uint4 pk;
      pk.x = pk2(v0.x, v0.y); pk.y = pk2(v0.z, v0.w);
      pk.z = pk2(v1.x, v1.y); pk.w = pk2(v1.z, v1.w);
      *(uint4*)&As[row*40 + off] = pk;
    }
    for (int i = t; i < 176*4; i += 512) {
      int c = i >> 2, off = (i & 3) * 8;
      *(uint4*)&Ws[c*40 + off] = *(const uint4*)(Wt + c*DIN + k0 + off);
    }
    __syncthreads();
    short8 a = *(const short8*)&As[(w*16 + r16)*40 + g4*8];
    #pragma unroll
    for (int f = 0; f < 11; ++f) {
      short8 b = *(const short8*)&Ws[(f*16 + r16)*40 + g4*8];
      acc[f] = __builtin_amdgcn_mfma_f32_16x16x32_bf16(a, b, acc[f], 0, 0, 0);
    }
    __syncthreads();
  }
  #pragma unroll
  for (int f = 0; f < 11; ++f) {
    int c = f*16 + r16;
    #pragma unroll
    for (int r = 0; r < 4; ++r) {
      int row = bm + w*16 + g4*4 + r;
      if (row >= M) continue;
      float v = acc[f][r];
      if (c < HD) hsb[(size_t)row*HD + c] = f2bf(v);
      else if (c < HD+DOUT) loopb[(size_t)row*DOUT + (c-HD)] = f2bf(v);
      else if (c < HD+DOUT+2*NH) scb[(size_t)row*8 + (c-(HD+DOUT))] = v;
    }
  }
}

// ---- CSR build ----
__global__ void hist_k(const int* __restrict__ d1, const int* __restrict__ d2,
                       int* __restrict__ deg) {
  int t = blockIdx.x*blockDim.x + threadIdx.x;
  if (t < EE) atomicAdd(&deg[d1[t]], 1);
  else if (t < 2*EE) atomicAdd(&deg[NN + d2[t-EE]], 1);
}

__global__ __launch_bounds__(256) void scan_sum(const int* __restrict__ deg, int* __restrict__ bsum) {
  int rel = blockIdx.y, b = blockIdx.x, t = threadIdx.x;
  int i = b*256 + t;
  int v = (i < NN) ? deg[rel*NN + i] : 0;
  int lane = t & 63, wv = t >> 6;
  #pragma unroll
  for (int st = 1; st < 64; st <<= 1) v += __shfl_xor(v, st);
  __shared__ int ws[4];
  if (lane == 0) ws[wv] = v;
  __syncthreads();
  if (t == 0) bsum[rel*NCH + b] = ws[0] + ws[1] + ws[2] + ws[3];
}

__global__ __launch_bounds__(256) void scan_mid(int* __restrict__ bsum, int* __restrict__ offs) {
  int rel = blockIdx.x;
  int* bs = bsum + rel*NCH;
  int t = threadIdx.x, lane = t & 63, wv = t >> 6;
  __shared__ int ws[4];
  int v = (t < NCH) ? bs[t] : 0;
  int x = v;
  #pragma unroll
  for (int st = 1; st < 64; st <<= 1) { int y = __shfl_up(x, st); if (lane >= st) x += y; }
  if (lane == 63) ws[wv] = x;
  __syncthreads();
  int add = 0;
  for (int ww = 0; ww < wv; ++ww) add += ws[ww];
  int exc = x - v + add;
  if (t < NCH) bs[t] = exc;
  if (t == 0) offs[rel*(NN+1) + NN] = ws[0] + ws[1] + ws[2] + ws[3];
}

__global__ __launch_bounds__(256) void scan_fin(const int* __restrict__ deg, const int* __restrict__ bsum,
                                                int* __restrict__ offs) {
  int rel = blockIdx.y, b = blockIdx.x, t = threadIdx.x;
  int i = b*256 + t;
  int v = (i < NN) ? deg[rel*NN + i] : 0;
  int lane = t & 63, wv = t >> 6;
  __shared__ int ws[4];
  int x = v;
  #pragma unroll
  for (int st = 1; st < 64; st <<= 1) { int y = __shfl_up(x, st); if (lane >= st) x += y; }
  if (lane == 63) ws[wv] = x;
  __syncthreads();
  int add = bsum[rel*NCH + b];
  for (int ww = 0; ww < wv; ++ww) add += ws[ww];
  int exc = x - v + add;
  if (i < NN) offs[rel*(NN+1) + i] = exc;
}

// coarse bin: entry = src | (dst&255)<<16 appended at bucket frontier
__global__ void bin_k(const int* __restrict__ s1, const int* __restrict__ d1,
                      const int* __restrict__ s2, const int* __restrict__ d2,
                      int* __restrict__ bc, unsigned* __restrict__ binned) {
  int t = blockIdx.x*blockDim.x + threadIdx.x;
  int rel, s, d;
  if (t < EE) { rel = 0; s = s1[t]; d = d1[t]; }
  else if (t < 2*EE) { rel = 1; s = s2[t-EE]; d = d2[t-EE]; }
  else return;
  int relb = rel*NB + (d >> 8);
  int pos = atomicAdd(&bc[relb], 1);
  if (pos < BCAP)
    binned[(size_t)relb*BCAP + pos] = (unsigned)s | ((unsigned)(d & 255) << 16);
}

// fine scatter: one wg per (bucket, rel); LDS-local placement, coalesced write-out
__global__ __launch_bounds__(256) void fine_k(const unsigned* __restrict__ binned,
                                              const int* __restrict__ offs,
                                              unsigned short* __restrict__ sorted1,
                                              unsigned short* __restrict__ sorted2) {
  __shared__ int cur[256];
  __shared__ unsigned short stag[BCAP];
  int b = blockIdx.x, rel = blockIdx.y, t = threadIdx.x;
  const int* of = offs + rel*(NN+1);
  unsigned short* sorted = rel ? sorted2 : sorted1;
  int d0 = b << 8;
  int nd = min(256, NN - d0);
  int segbase = of[d0];
  int total = of[d0 + nd] - segbase;
  if (t < nd) cur[t] = of[d0 + t] - segbase;
  __syncthreads();
  for (int i = t; i < total; i += 256) {
    unsigned e = binned[((size_t)(rel*NB + b))*BCAP + i];
    int dl = e >> 16;
    int pos = atomicAdd(&cur[dl], 1);
    if (pos < BCAP) stag[pos] = (unsigned short)(e & 0xffffu);
  }
  __syncthreads();
  for (int i = t; i < total; i += 256)
    sorted[segbase + i] = stag[i];
}

// one wave per (rel, dst): edge-parallel segment softmax -> normalized weights.
__global__ __launch_bounds__(256) void weight_k(const float* __restrict__ scU,
                                                const float* __restrict__ scI,
                                                const int* __restrict__ offs,
                                                const unsigned short* __restrict__ sorted1,
                                                const unsigned short* __restrict__ sorted2,
                                                float* __restrict__ w1,
                                                float* __restrict__ w2) {
  int gw = (blockIdx.x*blockDim.x + threadIdx.x) >> 6;
  if (gw >= 2*NN) return;
  int rel = gw >= NN;
  int d = rel ? gw - NN : gw;
  const float* sc_src = rel ? scI : scU;
  const float* sc_dst = rel ? scU : scI;
  const int*   of = offs + rel*(NN+1);
  const unsigned short* ss = rel ? sorted2 : sorted1;
  float*       wb = rel ? w2 : w1;
  int beg = of[d], end = of[d+1];
  if (beg >= end) return;
  int l = threadIdx.x & 63, h = l >> 4, q = l & 15;
  float er = sc_dst[(size_t)d*8 + 4 + h];
  float e_cache[4];
  float mx = -1e30f;
  int nch = 0;
  for (int p0 = beg; p0 < end; p0 += 16, ++nch) {
    int p = p0 + q;
    float e = -1e30f;
    if (p < end) {
      int s = ss[p];
      e = leakyf(sc_src[(size_t)s*8 + h] + er);
    }
    if (nch < 4) e_cache[nch] = e;
    mx = fmaxf(mx, e);
  }
  #pragma unroll
  for (int st = 1; st < 16; st <<= 1) mx = fmaxf(mx, __shfl_xor(mx, st));
  float dnp = 0.f;
  int c = 0;
  for (int p0 = beg; p0 < end; p0 += 16, ++c) {
    int p = p0 + q;
    float e;
    if (c < 4) e = e_cache[c];
    else {
      e = -1e30f;
      if (p < end) { int s = ss[p]; e = leakyf(sc_src[(size_t)s*8 + h] + er); }
    }
    float ex = (p < end) ? __expf(e - mx) : 0.f;
    if (c < 4) e_cache[c] = ex;
    dnp += ex;
  }
  #pragma unroll
  for (int st = 1; st < 16; st <<= 1) dnp += __shfl_xor(dnp, st);
  float rdn = 1.f / dnp;
  c = 0;
  for (int p0 = beg; p0 < end; p0 += 16, ++c) {
    int p = p0 + q;
    if (p < end) {
      float ex;
      if (c < 4) ex = e_cache[c];
      else { int s = ss[p]; ex = __expf(leakyf(sc_src[(size_t)s*8 + h] + er) - mx); }
      wb[(size_t)p*4 + h] = ex * rdn;
    }
  }
}

// one wave per (rel, dst): lane l covers cols 2l, 2l+1 (uint load = full 256B row/edge).
__global__ __launch_bounds__(256) void agg_k(const unsigned short* __restrict__ hsbU,
                                             const unsigned short* __restrict__ hsbI,
                                             const unsigned short* __restrict__ loopbU,
                                             const unsigned short* __restrict__ loopbI,
                                             const float* __restrict__ w1,
                                             const float* __restrict__ w2,
                                             const int* __restrict__ offs,
                                             const unsigned short* __restrict__ sorted1,
                                             const unsigned short* __restrict__ sorted2,
                                             float* __restrict__ out) {
  int gw = __builtin_amdgcn_readfirstlane((blockIdx.x*blockDim.x + threadIdx.x) >> 6);
  if (gw >= 2*NN) return;
  int rel = gw >= NN;
  int d = rel ? gw - NN : gw;
  const unsigned short* hsb = rel ? hsbI : hsbU;     // src features
  const unsigned short* lpb = rel ? loopbU : loopbI; // dst loop proj
  const float* wb = rel ? w2 : w1;
  const int*   of = offs + rel*(NN+1);
  const unsigned short* ss = rel ? sorted2 : sorted1;
  float* o = (rel ? out : out + (size_t)NN*HD) + (size_t)d*HD;
  int l = threadIdx.x & 63;
  int h = l >> 4;                       // head of cols 2l, 2l+1
  int beg = of[d], end = of[d+1];
  float aL0=0.f,aH0=0.f,aL1=0.f,aH1=0.f,aL2=0.f,aH2=0.f,aL3=0.f,aH3=0.f;
  int p = beg;
  for (; p + 4 <= end; p += 4) {
    int s0 = __builtin_amdgcn_readfirstlane((int)ss[p]);
    int s1 = __builtin_amdgcn_readfirstlane((int)ss[p+1]);
    int s2 = __builtin_amdgcn_readfirstlane((int)ss[p+2]);
    int s3 = __builtin_amdgcn_readfirstlane((int)ss[p+3]);
    float w0 = wb[(size_t)p*4 + h];
    float w1v = wb[(size_t)(p+1)*4 + h];
    float w2v = wb[(size_t)(p+2)*4 + h];
    float w3v = wb[(size_t)(p+3)*4 + h];
    unsigned r0 = *(const unsigned*)&hsb[(size_t)s0*HD + 2*l];
    unsigned r1 = *(const unsigned*)&hsb[(size_t)s1*HD + 2*l];
    unsigned r2 = *(const unsigned*)&hsb[(size_t)s2*HD + 2*l];
    unsigned r3 = *(const unsigned*)&hsb[(size_t)s3*HD + 2*l];
    aL0 = fmaf(w0,  bflo(r0), aL0); aH0 = fmaf(w0,  bfhi(r0), aH0);
    aL1 = fmaf(w1v, bflo(r1), aL1); aH1 = fmaf(w1v, bfhi(r1), aH1);
    aL2 = fmaf(w2v, bflo(r2), aL2); aH2 = fmaf(w2v, bfhi(r2), aH2);
    aL3 = fmaf(w3v, bflo(r3), aL3); aH3 = fmaf(w3v, bfhi(r3), aH3);
  }
  for (; p < end; ++p) {
    int s0 = __builtin_amdgcn_readfirstlane((int)ss[p]);
    float w0 = wb[(size_t)p*4 + h];
    unsigned r0 = *(const unsigned*)&hsb[(size_t)s0*HD + 2*l];
    aL0 = fmaf(w0, bflo(r0), aL0); aH0 = fmaf(w0, bfhi(r0), aH0);
  }
  float vL = eluf((aL0+aL1)+(aL2+aL3));
  float vH = eluf((aH0+aH1)+(aH2+aH3));
  unsigned lp2 = *(const unsigned*)&lpb[(size_t)d*DOUT + ((2*l) & 31)];
  vL = eluf(vL + bflo(lp2));
  vH = eluf(vH + bfhi(lp2));
  *(float2*)&o[2*l] = make_float2(vL, vH);
}

extern "C" void kernel_launch(void* const* d_in, const int* in_sizes, int n_in,
                              void* d_out, int out_size, void* d_ws, size_t ws_size,
                              hipStream_t stream) {
  const float* feat_user  = (const float*)d_in[0];
  const float* feat_item  = (const float*)d_in[1];
  const int*   src_r1     = (const int*)d_in[2];
  const int*   dst_r1     = (const int*)d_in[3];
  const int*   src_r2     = (const int*)d_in[4];
  const int*   dst_r2     = (const int*)d_in[5];
  const float* fc_r1      = (const float*)d_in[6];
  const float* attn_l_r1  = (const float*)d_in[7];
  const float* attn_r_r1  = (const float*)d_in[8];
  const float* fc_r2      = (const float*)d_in[9];
  const float* attn_l_r2  = (const float*)d_in[10];
  const float* attn_r_r2  = (const float*)d_in[11];
  const float* loopw      = (const float*)d_in[12];

  float* out = (float*)d_out;

  char* ws = (char*)d_ws;
  unsigned short* WtU   = (unsigned short*)ws;            ws += WC*DIN*2;
  unsigned short* WtI   = (unsigned short*)ws;            ws += WC*DIN*2;
  unsigned short* hsbU  = (unsigned short*)ws;            ws += (size_t)NU*HD*2;
  unsigned short* hsbI  = (unsigned short*)ws;            ws += (size_t)NI*HD*2;
  unsigned short* loopbU= (unsigned short*)ws;            ws += (size_t)NU*DOUT*2;
  unsigned short* loopbI= (unsigned short*)ws;            ws += (size_t)NI*DOUT*2;
  float*          scU   = (float*)ws;                     ws += (size_t)NU*8*4;
  float*          scI   = (float*)ws;                     ws += (size_t)NI*8*4;
  int*            deg   = (int*)ws;                       ws += 2*NN*4;
  int*            bc    = (int*)ws;                       ws += 2*NB*4;
  int*            offs  = (int*)ws;                       ws += 2*(NN+1)*4;
  int*            bsum  = (int*)ws;                       ws += 2*NCH*4;
  unsigned*       binned= (unsigned*)ws;                  ws += (size_t)2*NB*BCAP*4;
  unsigned short* sorted1=(unsigned short*)ws;            ws += (size_t)EE*2;
  unsigned short* sorted2=(unsigned short*)ws;            ws += (size_t)EE*2;
  float*          w1    = (float*)ws;                     ws += (size_t)EE*NH*4;
  float*          w2    = (float*)ws;                     ws += (size_t)EE*NH*4;

  // zero deg + bc in one shot (adjacent)
  hipMemsetAsync(deg, 0, sizeof(int)*(2*NN + 2*NB), stream);

  pack_wt<<<(WC*DIN+255)/256, 256, 0, stream>>>(fc_r1, attn_l_r1, fc_r2, attn_r_r2, loopw, WtU);
  pack_wt<<<(WC*DIN+255)/256, 256, 0, stream>>>(fc_r2, attn_l_r2, fc_r1, attn_r_r1, loopw, WtI);

  hist_k<<<(2*EE + 255)/256, 256, 0, stream>>>(dst_r1, dst_r2, deg);
  scan_sum<<<dim3(NCH,2), 256, 0, stream>>>(deg, bsum);
  scan_mid<<<2, 256, 0, stream>>>(bsum, offs);
  scan_fin<<<dim3(NCH,2), 256, 0, stream>>>(deg, bsum, offs);

  bin_k<<<(2*EE + 255)/256, 256, 0, stream>>>(src_r1, dst_r1, src_r2, dst_r2, bc, binned);
  fine_k<<<dim3(NB,2), 256, 0, stream>>>(binned, offs, sorted1, sorted2);

  gemm_mfma<<<(NU+127)/128, 512, 0, stream>>>(feat_user, WtU, hsbU, loopbU, scU, NU);
  gemm_mfma<<<(NI+127)/128, 512, 0, stream>>>(feat_item, WtI, hsbI, loopbI, scI, NI);

  weight_k<<<(2*NN*64 + 255)/256, 256, 0, stream>>>(scU, scI, offs, sorted1, sorted2, w1, w2);
  agg_k<<<(2*NN*64 + 255)/256, 256, 0, stream>>>(hsbU, hsbI, loopbU, loopbI, w1, w2,
                                                 offs, sorted1, sorted2, out);
}

// Round 7
// 265.692 us; speedup vs baseline: 3.8821x; 3.8821x over previous
//
#include <hip/hip_runtime.h>
#include <hip/hip_bf16.h>
#include <cstdint>

#define NU 50000
#define NI 50000
#define NN 50000
#define EE 800000
#define DIN 256
#define NH 4
#define DOUT 32
#define HD 128       // NH*DOUT
#define WC 176       // padded GEMM cols: [hs 128 | loop 32 | el 4 | er 4 | pad 8]
#define NCH 196      // ceil(NN/256)
#define NB 196       // dst buckets per relation (dst>>8)
#define NBR 200      // bin blocks per relation
#define NBLK 400     // total bin blocks
#define EPB 4000     // edges per bin block (EE/NBR)
#define SCAP 6144    // fine_k staging capacity (mean 4082, sigma 64)

typedef __attribute__((ext_vector_type(8))) short short8;
typedef __attribute__((ext_vector_type(4))) float f32x4;

__device__ __forceinline__ float leakyf(float x){ return x > 0.f ? x : 0.2f*x; }
__device__ __forceinline__ float eluf(float x){ return x > 0.f ? x : expm1f(x); }
__device__ __forceinline__ unsigned short f2bf(float x){
  unsigned u = __float_as_uint(x);
  return (unsigned short)((u + 0x7FFFu + ((u >> 16) & 1u)) >> 16);   // RNE
}
__device__ __forceinline__ float bf2f(unsigned short b){
  return __uint_as_float(((unsigned)b) << 16);
}
__device__ __forceinline__ float bflo(unsigned r){ return __uint_as_float(r << 16); }
__device__ __forceinline__ float bfhi(unsigned r){ return __uint_as_float(r & 0xffff0000u); }
__device__ __forceinline__ unsigned pk2(float x, float y){
  __hip_bfloat162 b = __float22bfloat162_rn(make_float2(x, y));
  union { __hip_bfloat162 b2; unsigned u; } c; c.b2 = b; return c.u;
}

// Wt[c][k] bf16, c<176 (cols 168-175 zero), k<256.
__global__ void pack_wt(const float* __restrict__ fc_a, const float* __restrict__ attn_l_a,
                        const float* __restrict__ fc_b, const float* __restrict__ attn_r_b,
                        const float* __restrict__ loopw, unsigned short* __restrict__ Wt) {
  int t = blockIdx.x*blockDim.x + threadIdx.x;
  if (t >= WC*DIN) return;
  int c = t >> 8, k = t & 255;
  float v = 0.f;
  if (c < HD) v = fc_a[k*HD + c];
  else if (c < HD+DOUT) v = loopw[k*DOUT + (c-HD)];
  else if (c < HD+DOUT+NH) {
    int h = c - (HD+DOUT); float s = 0.f;
    for (int dd = 0; dd < DOUT; ++dd) s += fc_a[k*HD + h*DOUT + dd] * attn_l_a[h*DOUT + dd];
    v = s;
  } else if (c < HD+DOUT+2*NH) {
    int h = c - (HD+DOUT+NH); float s = 0.f;
    for (int dd = 0; dd < DOUT; ++dd) s += fc_b[k*HD + h*DOUT + dd] * attn_r_b[h*DOUT + dd];
    v = s;
  }
  Wt[t] = f2bf(v);
}

// MFMA GEMM: A[M][256] f32 -> (A @ W)[M][176], split-written to hsb/loopb/scb.
__global__ __launch_bounds__(512) void gemm_mfma(const float* __restrict__ A,
                                                 const unsigned short* __restrict__ Wt,
                                                 unsigned short* __restrict__ hsb,
                                                 unsigned short* __restrict__ loopb,
                                                 float* __restrict__ scb, int M) {
  __shared__ __align__(16) unsigned short As[128*40];
  __shared__ __align__(16) unsigned short Ws[176*40];
  int t = threadIdx.x;
  int bm = blockIdx.x * 128;
  int w = t >> 6, l = t & 63;
  int r16 = l & 15, g4 = l >> 4;
  f32x4 acc[11];
  #pragma unroll
  for (int f = 0; f < 11; ++f) acc[f] = (f32x4){0.f,0.f,0.f,0.f};

  for (int k0 = 0; k0 < DIN; k0 += 32) {
    {
      int row = t >> 2, off = (t & 3) * 8;
      int gr = bm + row;
      float4 v0 = make_float4(0.f,0.f,0.f,0.f), v1 = v0;
      if (gr < M) {
        const float* ap = A + (size_t)gr*DIN + k0 + off;
        v0 = *(const float4*)ap;
        v1 = *(const float4*)(ap + 4);
      }
      uint4 pk;
      pk.x = pk2(v0.x, v0.y); pk.y = pk2(v0.z, v0.w);
      pk.z = pk2(v1.x, v1.y); pk.w = pk2(v1.z, v1.w);
      *(uint4*)&As[row*40 + off] = pk;
    }
    for (int i = t; i < 176*4; i += 512) {
      int c = i >> 2, off = (i & 3) * 8;
      *(uint4*)&Ws[c*40 + off] = *(const uint4*)(Wt + c*DIN + k0 + off);
    }
    __syncthreads();
    short8 a = *(const short8*)&As[(w*16 + r16)*40 + g4*8];
    #pragma unroll
    for (int f = 0; f < 11; ++f) {
      short8 b = *(const short8*)&Ws[(f*16 + r16)*40 + g4*8];
      acc[f] = __builtin_amdgcn_mfma_f32_16x16x32_bf16(a, b, acc[f], 0, 0, 0);
    }
    __syncthreads();
  }
  #pragma unroll
  for (int f = 0; f < 11; ++f) {
    int c = f*16 + r16;
    #pragma unroll
    for (int r = 0; r < 4; ++r) {
      int row = bm + w*16 + g4*4 + r;
      if (row >= M) continue;
      float v = acc[f][r];
      if (c < HD) hsb[(size_t)row*HD + c] = f2bf(v);
      else if (c < HD+DOUT) loopb[(size_t)row*DOUT + (c-HD)] = f2bf(v);
      else if (c < HD+DOUT+2*NH) scb[(size_t)row*8 + (c-(HD+DOUT))] = v;
    }
  }
}

// ---- CSR offsets ----
__global__ void hist_k(const int* __restrict__ d1, const int* __restrict__ d2,
                       int* __restrict__ deg) {
  int t = blockIdx.x*blockDim.x + threadIdx.x;
  if (t < EE) atomicAdd(&deg[d1[t]], 1);
  else if (t < 2*EE) atomicAdd(&deg[NN + d2[t-EE]], 1);
}

__global__ __launch_bounds__(256) void scan_sum(const int* __restrict__ deg, int* __restrict__ bsum) {
  int rel = blockIdx.y, b = blockIdx.x, t = threadIdx.x;
  int i = b*256 + t;
  int v = (i < NN) ? deg[rel*NN + i] : 0;
  int lane = t & 63, wv = t >> 6;
  #pragma unroll
  for (int st = 1; st < 64; st <<= 1) v += __shfl_xor(v, st);
  __shared__ int ws[4];
  if (lane == 0) ws[wv] = v;
  __syncthreads();
  if (t == 0) bsum[rel*NCH + b] = ws[0] + ws[1] + ws[2] + ws[3];
}

__global__ __launch_bounds__(256) void scan_mid(int* __restrict__ bsum, int* __restrict__ offs) {
  int rel = blockIdx.x;
  int* bs = bsum + rel*NCH;
  int t = threadIdx.x, lane = t & 63, wv = t >> 6;
  __shared__ int ws[4];
  int v = (t < NCH) ? bs[t] : 0;
  int x = v;
  #pragma unroll
  for (int st = 1; st < 64; st <<= 1) { int y = __shfl_up(x, st); if (lane >= st) x += y; }
  if (lane == 63) ws[wv] = x;
  __syncthreads();
  int add = 0;
  for (int ww = 0; ww < wv; ++ww) add += ws[ww];
  int exc = x - v + add;
  if (t < NCH) bs[t] = exc;
  if (t == 0) offs[rel*(NN+1) + NN] = ws[0] + ws[1] + ws[2] + ws[3];
}

__global__ __launch_bounds__(256) void scan_fin(const int* __restrict__ deg, const int* __restrict__ bsum,
                                                int* __restrict__ offs) {
  int rel = blockIdx.y, b = blockIdx.x, t = threadIdx.x;
  int i = b*256 + t;
  int v = (i < NN) ? deg[rel*NN + i] : 0;
  int lane = t & 63, wv = t >> 6;
  __shared__ int ws[4];
  int x = v;
  #pragma unroll
  for (int st = 1; st < 64; st <<= 1) { int y = __shfl_up(x, st); if (lane >= st) x += y; }
  if (lane == 63) ws[wv] = x;
  __syncthreads();
  int add = bsum[rel*NCH + b];
  for (int ww = 0; ww < wv; ++ww) add += ws[ww];
  int exc = x - v + add;
  if (i < NN) offs[rel*(NN+1) + i] = exc;
}

// ---- deterministic bucket sort (no global atomics) ----
// pass 1: per-block LDS histogram over 196 dst-buckets -> bhist[blk][196]
__global__ __launch_bounds__(256) void bhist_k(const int* __restrict__ d1,
                                               const int* __restrict__ d2,
                                               int* __restrict__ bhist) {
  __shared__ int hcnt[NB];
  int blk = blockIdx.x, t = threadIdx.x;
  for (int i = t; i < NB; i += 256) hcnt[i] = 0;
  __syncthreads();
  int rel = blk >= NBR;
  const int* dd = rel ? d2 : d1;
  int e0 = (rel ? blk - NBR : blk) * EPB;
  for (int i = t; i < EPB; i += 256) atomicAdd(&hcnt[dd[e0+i] >> 8], 1);
  __syncthreads();
  for (int i = t; i < NB; i += 256) bhist[blk*NB + i] = hcnt[i];
}

// pass 2: per bucket, exclusive-scan its 200 block counts + absolute base.
__global__ __launch_bounds__(256) void bscan_k(const int* __restrict__ offs,
                                               int* __restrict__ bhist) {
  int gb = blockIdx.x, t = threadIdx.x;
  int rel = gb >= NB, b = rel ? gb - NB : gb;
  int d0 = b << 8;
  int base = rel*EE + offs[rel*(NN+1) + d0];
  int v = (t < NBR) ? bhist[(rel*NBR + t)*NB + b] : 0;
  int lane = t & 63, wv = t >> 6;
  __shared__ int ws[4];
  int x = v;
  #pragma unroll
  for (int st = 1; st < 64; st <<= 1) { int y = __shfl_up(x, st); if (lane >= st) x += y; }
  if (lane == 63) ws[wv] = x;
  __syncthreads();
  int add = base;
  for (int ww = 0; ww < wv; ++ww) add += ws[ww];
  int exc = x - v + add;
  if (t < NBR) bhist[(rel*NBR + t)*NB + b] = exc;
}

// pass 3: place entries at exact positions (LDS cursors, no global atomics)
__global__ __launch_bounds__(256) void bscat_k(const int* __restrict__ s1, const int* __restrict__ d1,
                                               const int* __restrict__ s2, const int* __restrict__ d2,
                                               const int* __restrict__ bhist,
                                               unsigned* __restrict__ binned) {
  __shared__ int cur[NB];
  int blk = blockIdx.x, t = threadIdx.x;
  int rel = blk >= NBR;
  const int* ssrc = rel ? s2 : s1;
  const int* dd   = rel ? d2 : d1;
  int e0 = (rel ? blk - NBR : blk) * EPB;
  for (int i = t; i < NB; i += 256) cur[i] = bhist[blk*NB + i];
  __syncthreads();
  for (int i = t; i < EPB; i += 256) {
    int d = dd[e0+i], s = ssrc[e0+i];
    int pos = atomicAdd(&cur[d >> 8], 1);
    binned[pos] = (unsigned)s | ((unsigned)(d & 255) << 16);
  }
}

// pass 4: within-bucket sort by dst via LDS cursors, coalesced write-out
__global__ __launch_bounds__(256) void fine_k(const unsigned* __restrict__ binned,
                                              const int* __restrict__ offs,
                                              unsigned short* __restrict__ sorted1,
                                              unsigned short* __restrict__ sorted2) {
  __shared__ int cur[256];
  __shared__ unsigned short stag[SCAP];
  int b = blockIdx.x, rel = blockIdx.y, t = threadIdx.x;
  const int* of = offs + rel*(NN+1);
  unsigned short* sorted = rel ? sorted2 : sorted1;
  int d0 = b << 8;
  int nd = min(256, NN - d0);
  int segbase = of[d0];
  int total = of[d0 + nd] - segbase;
  if (t < nd) cur[t] = of[d0 + t] - segbase;
  __syncthreads();
  const unsigned* srcp = binned + (size_t)rel*EE + segbase;
  for (int i = t; i < total; i += 256) {
    unsigned e = srcp[i];
    int pos = atomicAdd(&cur[e >> 16], 1);
    if (pos < SCAP) stag[pos] = (unsigned short)(e & 0xffffu);
  }
  __syncthreads();
  for (int i = t; i < total; i += 256)
    sorted[segbase + i] = stag[i];
}

// one wave per (rel, dst): edge-parallel segment softmax -> normalized weights.
__global__ __launch_bounds__(256) void weight_k(const float* __restrict__ scU,
                                                const float* __restrict__ scI,
                                                const int* __restrict__ offs,
                                                const unsigned short* __restrict__ sorted1,
                                                const unsigned short* __restrict__ sorted2,
                                                float* __restrict__ w1,
                                                float* __restrict__ w2) {
  int gw = (blockIdx.x*blockDim.x + threadIdx.x) >> 6;
  if (gw >= 2*NN) return;
  int rel = gw >= NN;
  int d = rel ? gw - NN : gw;
  const float* sc_src = rel ? scI : scU;
  const float* sc_dst = rel ? scU : scI;
  const int*   of = offs + rel*(NN+1);
  const unsigned short* ss = rel ? sorted2 : sorted1;
  float*       wb = rel ? w2 : w1;
  int beg = of[d], end = of[d+1];
  if (beg >= end) return;
  int l = threadIdx.x & 63, h = l >> 4, q = l & 15;
  float er = sc_dst[(size_t)d*8 + 4 + h];
  float e_cache[4];
  float mx = -1e30f;
  int nch = 0;
  for (int p0 = beg; p0 < end; p0 += 16, ++nch) {
    int p = p0 + q;
    float e = -1e30f;
    if (p < end) {
      int s = ss[p];
      e = leakyf(sc_src[(size_t)s*8 + h] + er);
    }
    if (nch < 4) e_cache[nch] = e;
    mx = fmaxf(mx, e);
  }
  #pragma unroll
  for (int st = 1; st < 16; st <<= 1) mx = fmaxf(mx, __shfl_xor(mx, st));
  float dnp = 0.f;
  int c = 0;
  for (int p0 = beg; p0 < end; p0 += 16, ++c) {
    int p = p0 + q;
    float e;
    if (c < 4) e = e_cache[c];
    else {
      e = -1e30f;
      if (p < end) { int s = ss[p]; e = leakyf(sc_src[(size_t)s*8 + h] + er); }
    }
    float ex = (p < end) ? __expf(e - mx) : 0.f;
    if (c < 4) e_cache[c] = ex;
    dnp += ex;
  }
  #pragma unroll
  for (int st = 1; st < 16; st <<= 1) dnp += __shfl_xor(dnp, st);
  float rdn = 1.f / dnp;
  c = 0;
  for (int p0 = beg; p0 < end; p0 += 16, ++c) {
    int p = p0 + q;
    if (p < end) {
      float ex;
      if (c < 4) ex = e_cache[c];
      else { int s = ss[p]; ex = __expf(leakyf(sc_src[(size_t)s*8 + h] + er) - mx); }
      wb[(size_t)p*4 + h] = ex * rdn;
    }
  }
}

// one wave per (rel, dst): lane l covers cols 2l, 2l+1 (uint load = full 256B row/edge).
__global__ __launch_bounds__(256) void agg_k(const unsigned short* __restrict__ hsbU,
                                             const unsigned short* __restrict__ hsbI,
                                             const unsigned short* __restrict__ loopbU,
                                             const unsigned short* __restrict__ loopbI,
                                             const float* __restrict__ w1,
                                             const float* __restrict__ w2,
                                             const int* __restrict__ offs,
                                             const unsigned short* __restrict__ sorted1,
                                             const unsigned short* __restrict__ sorted2,
                                             float* __restrict__ out) {
  int gw = __builtin_amdgcn_readfirstlane((blockIdx.x*blockDim.x + threadIdx.x) >> 6);
  if (gw >= 2*NN) return;
  int rel = gw >= NN;
  int d = rel ? gw - NN : gw;
  const unsigned short* hsb = rel ? hsbI : hsbU;     // src features
  const unsigned short* lpb = rel ? loopbU : loopbI; // dst loop proj
  const float* wb = rel ? w2 : w1;
  const int*   of = offs + rel*(NN+1);
  const unsigned short* ss = rel ? sorted2 : sorted1;
  float* o = (rel ? out : out + (size_t)NN*HD) + (size_t)d*HD;
  int l = threadIdx.x & 63;
  int h = l >> 4;                       // head of cols 2l, 2l+1
  int beg = of[d], end = of[d+1];
  float aL0=0.f,aH0=0.f,aL1=0.f,aH1=0.f,aL2=0.f,aH2=0.f,aL3=0.f,aH3=0.f;
  int p = beg;
  for (; p + 4 <= end; p += 4) {
    int s0 = __builtin_amdgcn_readfirstlane((int)ss[p]);
    int s1 = __builtin_amdgcn_readfirstlane((int)ss[p+1]);
    int s2 = __builtin_amdgcn_readfirstlane((int)ss[p+2]);
    int s3 = __builtin_amdgcn_readfirstlane((int)ss[p+3]);
    float w0 = wb[(size_t)p*4 + h];
    float w1v = wb[(size_t)(p+1)*4 + h];
    float w2v = wb[(size_t)(p+2)*4 + h];
    float w3v = wb[(size_t)(p+3)*4 + h];
    unsigned r0 = *(const unsigned*)&hsb[(size_t)s0*HD + 2*l];
    unsigned r1 = *(const unsigned*)&hsb[(size_t)s1*HD + 2*l];
    unsigned r2 = *(const unsigned*)&hsb[(size_t)s2*HD + 2*l];
    unsigned r3 = *(const unsigned*)&hsb[(size_t)s3*HD + 2*l];
    aL0 = fmaf(w0,  bflo(r0), aL0); aH0 = fmaf(w0,  bfhi(r0), aH0);
    aL1 = fmaf(w1v, bflo(r1), aL1); aH1 = fmaf(w1v, bfhi(r1), aH1);
    aL2 = fmaf(w2v, bflo(r2), aL2); aH2 = fmaf(w2v, bfhi(r2), aH2);
    aL3 = fmaf(w3v, bflo(r3), aL3); aH3 = fmaf(w3v, bfhi(r3), aH3);
  }
  for (; p < end; ++p) {
    int s0 = __builtin_amdgcn_readfirstlane((int)ss[p]);
    float w0 = wb[(size_t)p*4 + h];
    unsigned r0 = *(const unsigned*)&hsb[(size_t)s0*HD + 2*l];
    aL0 = fmaf(w0, bflo(r0), aL0); aH0 = fmaf(w0, bfhi(r0), aH0);
  }
  float vL = eluf((aL0+aL1)+(aL2+aL3));
  float vH = eluf((aH0+aH1)+(aH2+aH3));
  unsigned lp2 = *(const unsigned*)&lpb[(size_t)d*DOUT + ((2*l) & 31)];
  vL = eluf(vL + bflo(lp2));
  vH = eluf(vH + bfhi(lp2));
  *(float2*)&o[2*l] = make_float2(vL, vH);
}

extern "C" void kernel_launch(void* const* d_in, const int* in_sizes, int n_in,
                              void* d_out, int out_size, void* d_ws, size_t ws_size,
                              hipStream_t stream) {
  const float* feat_user  = (const float*)d_in[0];
  const float* feat_item  = (const float*)d_in[1];
  const int*   src_r1     = (const int*)d_in[2];
  const int*   dst_r1     = (const int*)d_in[3];
  const int*   src_r2     = (const int*)d_in[4];
  const int*   dst_r2     = (const int*)d_in[5];
  const float* fc_r1      = (const float*)d_in[6];
  const float* attn_l_r1  = (const float*)d_in[7];
  const float* attn_r_r1  = (const float*)d_in[8];
  const float* fc_r2      = (const float*)d_in[9];
  const float* attn_l_r2  = (const float*)d_in[10];
  const float* attn_r_r2  = (const float*)d_in[11];
  const float* loopw      = (const float*)d_in[12];

  float* out = (float*)d_out;

  char* ws = (char*)d_ws;
  unsigned short* WtU   = (unsigned short*)ws;            ws += WC*DIN*2;
  unsigned short* WtI   = (unsigned short*)ws;            ws += WC*DIN*2;
  unsigned short* hsbU  = (unsigned short*)ws;            ws += (size_t)NU*HD*2;
  unsigned short* hsbI  = (unsigned short*)ws;            ws += (size_t)NI*HD*2;
  unsigned short* loopbU= (unsigned short*)ws;            ws += (size_t)NU*DOUT*2;
  unsigned short* loopbI= (unsigned short*)ws;            ws += (size_t)NI*DOUT*2;
  float*          scU   = (float*)ws;                     ws += (size_t)NU*8*4;
  float*          scI   = (float*)ws;                     ws += (size_t)NI*8*4;
  int*            deg   = (int*)ws;                       ws += 2*NN*4;
  int*            offs  = (int*)ws;                       ws += 2*(NN+1)*4;
  int*            bsum  = (int*)ws;                       ws += 2*NCH*4;
  int*            bhist = (int*)ws;                       ws += (size_t)NBLK*NB*4;
  unsigned*       binned= (unsigned*)ws;                  ws += (size_t)2*EE*4;
  unsigned short* sorted1=(unsigned short*)ws;            ws += (size_t)EE*2;
  unsigned short* sorted2=(unsigned short*)ws;            ws += (size_t)EE*2;
  float*          w1    = (float*)ws;                     ws += (size_t)EE*NH*4;
  float*          w2    = (float*)ws;                     ws += (size_t)EE*NH*4;

  hipMemsetAsync(deg, 0, sizeof(int)*2*NN, stream);

  pack_wt<<<(WC*DIN+255)/256, 256, 0, stream>>>(fc_r1, attn_l_r1, fc_r2, attn_r_r2, loopw, WtU);
  pack_wt<<<(WC*DIN+255)/256, 256, 0, stream>>>(fc_r2, attn_l_r2, fc_r1, attn_r_r1, loopw, WtI);

  hist_k<<<(2*EE + 255)/256, 256, 0, stream>>>(dst_r1, dst_r2, deg);
  scan_sum<<<dim3(NCH,2), 256, 0, stream>>>(deg, bsum);
  scan_mid<<<2, 256, 0, stream>>>(bsum, offs);
  scan_fin<<<dim3(NCH,2), 256, 0, stream>>>(deg, bsum, offs);

  bhist_k<<<NBLK, 256, 0, stream>>>(dst_r1, dst_r2, bhist);
  bscan_k<<<2*NB, 256, 0, stream>>>(offs, bhist);
  bscat_k<<<NBLK, 256, 0, stream>>>(src_r1, dst_r1, src_r2, dst_r2, bhist, binned);
  fine_k<<<dim3(NB,2), 256, 0, stream>>>(binned, offs, sorted1, sorted2);

  gemm_mfma<<<(NU+127)/128, 512, 0, stream>>>(feat_user, WtU, hsbU, loopbU, scU, NU);
  gemm_mfma<<<(NI+127)/128, 512, 0, stream>>>(feat_item, WtI, hsbI, loopbI, scI, NI);

  weight_k<<<(2*NN*64 + 255)/256, 256, 0, stream>>>(scU, scI, offs, sorted1, sorted2, w1, w2);
  agg_k<<<(2*NN*64 + 255)/256, 256, 0, stream>>>(hsbU, hsbI, loopbU, loopbI, w1, w2,
                                                 offs, sorted1, sorted2, out);
}

// Round 8
// 195.852 us; speedup vs baseline: 5.2664x; 1.3566x over previous
//
#include <hip/hip_runtime.h>
#include <hip/hip_bf16.h>
#include <cstdint>

#define NU 50000
#define NI 50000
#define NN 50000
#define EE 800000
#define DIN 256
#define NH 4
#define DOUT 32
#define HD 128       // NH*DOUT
#define WC 176       // padded GEMM cols: [hs 128 | loop 32 | el 4 | er 4 | pad 8]
#define NB 196       // dst buckets per relation (dst>>8)
#define NBR 200      // bin blocks per relation
#define NBLK 400     // total bin blocks
#define EPB 4000     // edges per bin block (EE/NBR)
#define SCAP 6144    // fine_k staging capacity (mean 4082, sigma 64)

typedef __attribute__((ext_vector_type(8))) short short8;
typedef __attribute__((ext_vector_type(4))) float f32x4;

__device__ __forceinline__ float leakyf(float x){ return x > 0.f ? x : 0.2f*x; }
__device__ __forceinline__ float eluf(float x){ return x > 0.f ? x : expm1f(x); }
__device__ __forceinline__ unsigned short f2bf(float x){
  unsigned u = __float_as_uint(x);
  return (unsigned short)((u + 0x7FFFu + ((u >> 16) & 1u)) >> 16);   // RNE
}
__device__ __forceinline__ float bf2f(unsigned short b){
  return __uint_as_float(((unsigned)b) << 16);
}
__device__ __forceinline__ float bflo(unsigned r){ return __uint_as_float(r << 16); }
__device__ __forceinline__ float bfhi(unsigned r){ return __uint_as_float(r & 0xffff0000u); }
__device__ __forceinline__ unsigned pk2(float x, float y){
  __hip_bfloat162 b = __float22bfloat162_rn(make_float2(x, y));
  union { __hip_bfloat162 b2; unsigned u; } c; c.b2 = b; return c.u;
}

// Wt[c][k] bf16, c<176 (cols 168-175 zero), k<256.
__global__ void pack_wt(const float* __restrict__ fc_a, const float* __restrict__ attn_l_a,
                        const float* __restrict__ fc_b, const float* __restrict__ attn_r_b,
                        const float* __restrict__ loopw, unsigned short* __restrict__ Wt) {
  int t = blockIdx.x*blockDim.x + threadIdx.x;
  if (t >= WC*DIN) return;
  int c = t >> 8, k = t & 255;
  float v = 0.f;
  if (c < HD) v = fc_a[k*HD + c];
  else if (c < HD+DOUT) v = loopw[k*DOUT + (c-HD)];
  else if (c < HD+DOUT+NH) {
    int h = c - (HD+DOUT); float s = 0.f;
    for (int dd = 0; dd < DOUT; ++dd) s += fc_a[k*HD + h*DOUT + dd] * attn_l_a[h*DOUT + dd];
    v = s;
  } else if (c < HD+DOUT+2*NH) {
    int h = c - (HD+DOUT+NH); float s = 0.f;
    for (int dd = 0; dd < DOUT; ++dd) s += fc_b[k*HD + h*DOUT + dd] * attn_r_b[h*DOUT + dd];
    v = s;
  }
  Wt[t] = f2bf(v);
}

// MFMA GEMM, double-buffered LDS, one barrier per K-tile.
__global__ __launch_bounds__(512) void gemm_mfma(const float* __restrict__ A,
                                                 const unsigned short* __restrict__ Wt,
                                                 unsigned short* __restrict__ hsb,
                                                 unsigned short* __restrict__ loopb,
                                                 float* __restrict__ scb, int M) {
  __shared__ __align__(16) unsigned short As[2][128*40];
  __shared__ __align__(16) unsigned short Ws[2][176*40];
  int t = threadIdx.x;
  int bm = blockIdx.x * 128;
  int w = t >> 6, l = t & 63;
  int r16 = l & 15, g4 = l >> 4;
  f32x4 acc[11];
  #pragma unroll
  for (int f = 0; f < 11; ++f) acc[f] = (f32x4){0.f,0.f,0.f,0.f};

  int arow = t >> 2, aoff = (t & 3) * 8;
  int gr = bm + arow;
  int wc0 = t >> 2, woff0 = (t & 3) * 8;          // W entry i = t  (c in 0..127)
  int wc1 = (t + 512) >> 2, woff1 = (t & 3) * 8;  // W entry i = t+512 (c in 128..175), t<192

  float4 a0, a1;
  uint4 wa, wb;
  auto loadT = [&](int k0) {
    a0 = make_float4(0.f,0.f,0.f,0.f); a1 = a0;
    if (gr < M) {
      const float* ap = A + (size_t)gr*DIN + k0 + aoff;
      a0 = *(const float4*)ap; a1 = *(const float4*)(ap + 4);
    }
    wa = *(const uint4*)(Wt + wc0*DIN + k0 + woff0);
    if (t < 192) wb = *(const uint4*)(Wt + wc1*DIN + k0 + woff1);
  };
  auto storeT = [&](int buf) {
    uint4 pk;
    pk.x = pk2(a0.x, a0.y); pk.y = pk2(a0.z, a0.w);
    pk.z = pk2(a1.x, a1.y); pk.w = pk2(a1.z, a1.w);
    *(uint4*)&As[buf][arow*40 + aoff] = pk;
    *(uint4*)&Ws[buf][wc0*40 + woff0] = wa;
    if (t < 192) *(uint4*)&Ws[buf][wc1*40 + woff1] = wb;
  };

  loadT(0);
  storeT(0);
  #pragma unroll
  for (int kt = 0; kt < 8; ++kt) {
    int cur = kt & 1;
    if (kt < 7) loadT((kt + 1) * 32);
    __syncthreads();
    short8 a = *(const short8*)&As[cur][(w*16 + r16)*40 + g4*8];
    #pragma unroll
    for (int f = 0; f < 11; ++f) {
      short8 b = *(const short8*)&Ws[cur][(f*16 + r16)*40 + g4*8];
      acc[f] = __builtin_amdgcn_mfma_f32_16x16x32_bf16(a, b, acc[f], 0, 0, 0);
    }
    if (kt < 7) storeT(cur ^ 1);
  }
  #pragma unroll
  for (int f = 0; f < 11; ++f) {
    int c = f*16 + r16;
    #pragma unroll
    for (int r = 0; r < 4; ++r) {
      int row = bm + w*16 + g4*4 + r;
      if (row >= M) continue;
      float v = acc[f][r];
      if (c < HD) hsb[(size_t)row*HD + c] = f2bf(v);
      else if (c < HD+DOUT) loopb[(size_t)row*DOUT + (c-HD)] = f2bf(v);
      else if (c < HD+DOUT+2*NH) scb[(size_t)row*8 + (c-(HD+DOUT))] = v;
    }
  }
}

// ---- deterministic bucket sort; also produces CSR offs ----
// pass 1: per-block LDS histogram over 196 dst-buckets -> bhist[blk][196]
__global__ __launch_bounds__(256) void bhist_k(const int* __restrict__ d1,
                                               const int* __restrict__ d2,
                                               int* __restrict__ bhist) {
  __shared__ int hcnt[NB];
  int blk = blockIdx.x, t = threadIdx.x;
  for (int i = t; i < NB; i += 256) hcnt[i] = 0;
  __syncthreads();
  int rel = blk >= NBR;
  const int* dd = rel ? d2 : d1;
  int e0 = (rel ? blk - NBR : blk) * EPB;
  for (int i = t; i < EPB; i += 256) atomicAdd(&hcnt[dd[e0+i] >> 8], 1);
  __syncthreads();
  for (int i = t; i < NB; i += 256) bhist[blk*NB + i] = hcnt[i];
}

// pass 2a: bucket totals -> exclusive scan -> bucketbase[rel][b] (within-relation)
__global__ __launch_bounds__(256) void btot_k(const int* __restrict__ bhist,
                                              int* __restrict__ bucketbase,
                                              int* __restrict__ offs) {
  int rel = blockIdx.x, t = threadIdx.x;
  int tot = 0;
  if (t < NB)
    for (int blk = 0; blk < NBR; ++blk) tot += bhist[(rel*NBR + blk)*NB + t];
  int lane = t & 63, wv = t >> 6;
  __shared__ int ws[4];
  int x = tot;
  #pragma unroll
  for (int st = 1; st < 64; st <<= 1) { int y = __shfl_up(x, st); if (lane >= st) x += y; }
  if (lane == 63) ws[wv] = x;
  __syncthreads();
  int add = 0;
  for (int ww = 0; ww < wv; ++ww) add += ws[ww];
  int exc = x - tot + add;
  if (t < NB) bucketbase[rel*(NB+1) + t] = exc;
  if (t == 0) {
    bucketbase[rel*(NB+1) + NB] = EE;
    offs[rel*(NN+1) + NN] = EE;
  }
}

// pass 2b: per bucket, exclusive-scan its 200 block counts + absolute base
__global__ __launch_bounds__(256) void bscan_k(const int* __restrict__ bucketbase,
                                               int* __restrict__ bhist) {
  int gb = blockIdx.x, t = threadIdx.x;
  int rel = gb >= NB, b = rel ? gb - NB : gb;
  int base = rel*EE + bucketbase[rel*(NB+1) + b];
  int v = (t < NBR) ? bhist[(rel*NBR + t)*NB + b] : 0;
  int lane = t & 63, wv = t >> 6;
  __shared__ int ws[4];
  int x = v;
  #pragma unroll
  for (int st = 1; st < 64; st <<= 1) { int y = __shfl_up(x, st); if (lane >= st) x += y; }
  if (lane == 63) ws[wv] = x;
  __syncthreads();
  int add = base;
  for (int ww = 0; ww < wv; ++ww) add += ws[ww];
  int exc = x - v + add;
  if (t < NBR) bhist[(rel*NBR + t)*NB + b] = exc;
}

// pass 3: place entries at exact positions (LDS cursors, no global atomics)
__global__ __launch_bounds__(256) void bscat_k(const int* __restrict__ s1, const int* __restrict__ d1,
                                               const int* __restrict__ s2, const int* __restrict__ d2,
                                               const int* __restrict__ bhist,
                                               unsigned* __restrict__ binned) {
  __shared__ int cur[NB];
  int blk = blockIdx.x, t = threadIdx.x;
  int rel = blk >= NBR;
  const int* ssrc = rel ? s2 : s1;
  const int* dd   = rel ? d2 : d1;
  int e0 = (rel ? blk - NBR : blk) * EPB;
  for (int i = t; i < NB; i += 256) cur[i] = bhist[blk*NB + i];
  __syncthreads();
  for (int i = t; i < EPB; i += 256) {
    int d = dd[e0+i], s = ssrc[e0+i];
    int pos = atomicAdd(&cur[d >> 8], 1);
    binned[pos] = (unsigned)s | ((unsigned)(d & 255) << 16);
  }
}

// pass 4: within-bucket sort by dst; derives per-dst CSR offs locally.
__global__ __launch_bounds__(256) void fine_k(const unsigned* __restrict__ binned,
                                              const int* __restrict__ bucketbase,
                                              int* __restrict__ offs,
                                              unsigned short* __restrict__ sorted1,
                                              unsigned short* __restrict__ sorted2) {
  __shared__ int cnt[256];
  __shared__ int cur[256];
  __shared__ int ws[4];
  __shared__ unsigned short stag[SCAP];
  int b = blockIdx.x, rel = blockIdx.y, t = threadIdx.x;
  unsigned short* sorted = rel ? sorted2 : sorted1;
  int d0 = b << 8;
  int nd = min(256, NN - d0);
  int base = bucketbase[rel*(NB+1) + b];
  int total = bucketbase[rel*(NB+1) + b + 1] - base;
  cnt[t] = 0;
  __syncthreads();
  const unsigned* srcp = binned + (size_t)rel*EE + base;
  for (int i = t; i < total; i += 256) atomicAdd(&cnt[srcp[i] >> 16], 1);
  __syncthreads();
  int v = cnt[t];
  int lane = t & 63, wv = t >> 6;
  int x = v;
  #pragma unroll
  for (int st = 1; st < 64; st <<= 1) { int y = __shfl_up(x, st); if (lane >= st) x += y; }
  if (lane == 63) ws[wv] = x;
  __syncthreads();
  int add = 0;
  for (int ww = 0; ww < wv; ++ww) add += ws[ww];
  int exc = x - v + add;
  cur[t] = exc;
  if (t < nd) offs[rel*(NN+1) + d0 + t] = base + exc;
  __syncthreads();
  for (int i = t; i < total; i += 256) {
    unsigned e = srcp[i];
    int pos = atomicAdd(&cur[e >> 16], 1);
    if (pos < SCAP) stag[pos] = (unsigned short)(e & 0xffffu);
  }
  __syncthreads();
  for (int i = t; i < total; i += 256)
    sorted[base + i] = stag[i];
}

// one wave per (rel, dst): edge-parallel segment softmax -> normalized bf16 weights.
__global__ __launch_bounds__(256) void weight_k(const float* __restrict__ scU,
                                                const float* __restrict__ scI,
                                                const int* __restrict__ offs,
                                                const unsigned short* __restrict__ sorted1,
                                                const unsigned short* __restrict__ sorted2,
                                                unsigned short* __restrict__ w1,
                                                unsigned short* __restrict__ w2) {
  int gw = (blockIdx.x*blockDim.x + threadIdx.x) >> 6;
  if (gw >= 2*NN) return;
  int rel = gw >= NN;
  int d = rel ? gw - NN : gw;
  const float* sc_src = rel ? scI : scU;
  const float* sc_dst = rel ? scU : scI;
  const int*   of = offs + rel*(NN+1);
  const unsigned short* ss = rel ? sorted2 : sorted1;
  unsigned short* wb = rel ? w2 : w1;
  int beg = of[d], end = of[d+1];
  if (beg >= end) return;
  int l = threadIdx.x & 63, h = l >> 4, q = l & 15;
  float er = sc_dst[(size_t)d*8 + 4 + h];
  float e_cache[4];
  float mx = -1e30f;
  int nch = 0;
  for (int p0 = beg; p0 < end; p0 += 16, ++nch) {
    int p = p0 + q;
    float e = -1e30f;
    if (p < end) {
      int s = ss[p];
      e = leakyf(sc_src[(size_t)s*8 + h] + er);
    }
    if (nch < 4) e_cache[nch] = e;
    mx = fmaxf(mx, e);
  }
  #pragma unroll
  for (int st = 1; st < 16; st <<= 1) mx = fmaxf(mx, __shfl_xor(mx, st));
  float dnp = 0.f;
  int c = 0;
  for (int p0 = beg; p0 < end; p0 += 16, ++c) {
    int p = p0 + q;
    float e;
    if (c < 4) e = e_cache[c];
    else {
      e = -1e30f;
      if (p < end) { int s = ss[p]; e = leakyf(sc_src[(size_t)s*8 + h] + er); }
    }
    float ex = (p < end) ? __expf(e - mx) : 0.f;
    if (c < 4) e_cache[c] = ex;
    dnp += ex;
  }
  #pragma unroll
  for (int st = 1; st < 16; st <<= 1) dnp += __shfl_xor(dnp, st);
  float rdn = 1.f / dnp;
  c = 0;
  for (int p0 = beg; p0 < end; p0 += 16, ++c) {
    int p = p0 + q;
    if (p < end) {
      float ex;
      if (c < 4) ex = e_cache[c];
      else { int s = ss[p]; ex = __expf(leakyf(sc_src[(size_t)s*8 + h] + er) - mx); }
      wb[(size_t)p*4 + h] = f2bf(ex * rdn);
    }
  }
}

// one wave per (rel, dst): lane l covers cols 2l, 2l+1; unroll 8 for MLP.
__global__ __launch_bounds__(256) void agg_k(const unsigned short* __restrict__ hsbU,
                                             const unsigned short* __restrict__ hsbI,
                                             const unsigned short* __restrict__ loopbU,
                                             const unsigned short* __restrict__ loopbI,
                                             const unsigned short* __restrict__ w1,
                                             const unsigned short* __restrict__ w2,
                                             const int* __restrict__ offs,
                                             const unsigned short* __restrict__ sorted1,
                                             const unsigned short* __restrict__ sorted2,
                                             float* __restrict__ out) {
  int gw = __builtin_amdgcn_readfirstlane((blockIdx.x*blockDim.x + threadIdx.x) >> 6);
  if (gw >= 2*NN) return;
  int rel = gw >= NN;
  int d = rel ? gw - NN : gw;
  const unsigned short* hsb = rel ? hsbI : hsbU;     // src features
  const unsigned short* lpb = rel ? loopbU : loopbI; // dst loop proj
  const unsigned short* wb = rel ? w2 : w1;
  const int*   of = offs + rel*(NN+1);
  const unsigned short* ss = rel ? sorted2 : sorted1;
  float* o = (rel ? out : out + (size_t)NN*HD) + (size_t)d*HD;
  int l = threadIdx.x & 63;
  int h = l >> 4;                       // head of cols 2l, 2l+1
  int beg = of[d], end = of[d+1];
  float aL0=0.f,aH0=0.f,aL1=0.f,aH1=0.f,aL2=0.f,aH2=0.f,aL3=0.f,aH3=0.f;
  int p = beg;
  for (; p + 8 <= end; p += 8) {
    int s0 = __builtin_amdgcn_readfirstlane((int)ss[p]);
    int s1 = __builtin_amdgcn_readfirstlane((int)ss[p+1]);
    int s2 = __builtin_amdgcn_readfirstlane((int)ss[p+2]);
    int s3 = __builtin_amdgcn_readfirstlane((int)ss[p+3]);
    int s4 = __builtin_amdgcn_readfirstlane((int)ss[p+4]);
    int s5 = __builtin_amdgcn_readfirstlane((int)ss[p+5]);
    int s6 = __builtin_amdgcn_readfirstlane((int)ss[p+6]);
    int s7 = __builtin_amdgcn_readfirstlane((int)ss[p+7]);
    float w0 = bf2f(wb[(size_t)p*4 + h]);
    float w1v = bf2f(wb[(size_t)(p+1)*4 + h]);
    float w2v = bf2f(wb[(size_t)(p+2)*4 + h]);
    float w3v = bf2f(wb[(size_t)(p+3)*4 + h]);
    float w4v = bf2f(wb[(size_t)(p+4)*4 + h]);
    float w5v = bf2f(wb[(size_t)(p+5)*4 + h]);
    float w6v = bf2f(wb[(size_t)(p+6)*4 + h]);
    float w7v = bf2f(wb[(size_t)(p+7)*4 + h]);
    unsigned r0 = *(const unsigned*)&hsb[(size_t)s0*HD + 2*l];
    unsigned r1 = *(const unsigned*)&hsb[(size_t)s1*HD + 2*l];
    unsigned r2 = *(const unsigned*)&hsb[(size_t)s2*HD + 2*l];
    unsigned r3 = *(const unsigned*)&hsb[(size_t)s3*HD + 2*l];
    unsigned r4 = *(const unsigned*)&hsb[(size_t)s4*HD + 2*l];
    unsigned r5 = *(const unsigned*)&hsb[(size_t)s5*HD + 2*l];
    unsigned r6 = *(const unsigned*)&hsb[(size_t)s6*HD + 2*l];
    unsigned r7 = *(const unsigned*)&hsb[(size_t)s7*HD + 2*l];
    aL0 = fmaf(w0,  bflo(r0), aL0); aH0 = fmaf(w0,  bfhi(r0), aH0);
    aL1 = fmaf(w1v, bflo(r1), aL1); aH1 = fmaf(w1v, bfhi(r1), aH1);
    aL2 = fmaf(w2v, bflo(r2), aL2); aH2 = fmaf(w2v, bfhi(r2), aH2);
    aL3 = fmaf(w3v, bflo(r3), aL3); aH3 = fmaf(w3v, bfhi(r3), aH3);
    aL0 = fmaf(w4v, bflo(r4), aL0); aH0 = fmaf(w4v, bfhi(r4), aH0);
    aL1 = fmaf(w5v, bflo(r5), aL1); aH1 = fmaf(w5v, bfhi(r5), aH1);
    aL2 = fmaf(w6v, bflo(r6), aL2); aH2 = fmaf(w6v, bfhi(r6), aH2);
    aL3 = fmaf(w7v, bflo(r7), aL3); aH3 = fmaf(w7v, bfhi(r7), aH3);
  }
  for (; p < end; ++p) {
    int s0 = __builtin_amdgcn_readfirstlane((int)ss[p]);
    float w0 = bf2f(wb[(size_t)p*4 + h]);
    unsigned r0 = *(const unsigned*)&hsb[(size_t)s0*HD + 2*l];
    aL0 = fmaf(w0, bflo(r0), aL0); aH0 = fmaf(w0, bfhi(r0), aH0);
  }
  float vL = eluf((aL0+aL1)+(aL2+aL3));
  float vH = eluf((aH0+aH1)+(aH2+aH3));
  unsigned lp2 = *(const unsigned*)&lpb[(size_t)d*DOUT + ((2*l) & 31)];
  vL = eluf(vL + bflo(lp2));
  vH = eluf(vH + bfhi(lp2));
  *(float2*)&o[2*l] = make_float2(vL, vH);
}

extern "C" void kernel_launch(void* const* d_in, const int* in_sizes, int n_in,
                              void* d_out, int out_size, void* d_ws, size_t ws_size,
                              hipStream_t stream) {
  const float* feat_user  = (const float*)d_in[0];
  const float* feat_item  = (const float*)d_in[1];
  const int*   src_r1     = (const int*)d_in[2];
  const int*   dst_r1     = (const int*)d_in[3];
  const int*   src_r2     = (const int*)d_in[4];
  const int*   dst_r2     = (const int*)d_in[5];
  const float* fc_r1      = (const float*)d_in[6];
  const float* attn_l_r1  = (const float*)d_in[7];
  const float* attn_r_r1  = (const float*)d_in[8];
  const float* fc_r2      = (const float*)d_in[9];
  const float* attn_l_r2  = (const float*)d_in[10];
  const float* attn_r_r2  = (const float*)d_in[11];
  const float* loopw      = (const float*)d_in[12];

  float* out = (float*)d_out;

  char* ws = (char*)d_ws;
  unsigned short* WtU   = (unsigned short*)ws;            ws += WC*DIN*2;
  unsigned short* WtI   = (unsigned short*)ws;            ws += WC*DIN*2;
  unsigned short* hsbU  = (unsigned short*)ws;            ws += (size_t)NU*HD*2;
  unsigned short* hsbI  = (unsigned short*)ws;            ws += (size_t)NI*HD*2;
  unsigned short* loopbU= (unsigned short*)ws;            ws += (size_t)NU*DOUT*2;
  unsigned short* loopbI= (unsigned short*)ws;            ws += (size_t)NI*DOUT*2;
  float*          scU   = (float*)ws;                     ws += (size_t)NU*8*4;
  float*          scI   = (float*)ws;                     ws += (size_t)NI*8*4;
  int*            offs  = (int*)ws;                       ws += 2*(NN+1)*4;
  int*            bktb  = (int*)ws;                       ws += 2*(NB+1)*4;
  int*            bhist = (int*)ws;                       ws += (size_t)NBLK*NB*4;
  unsigned*       binned= (unsigned*)ws;                  ws += (size_t)2*EE*4;
  unsigned short* sorted1=(unsigned short*)ws;            ws += (size_t)EE*2;
  unsigned short* sorted2=(unsigned short*)ws;            ws += (size_t)EE*2;
  unsigned short* w1    = (unsigned short*)ws;            ws += (size_t)EE*NH*2;
  unsigned short* w2    = (unsigned short*)ws;            ws += (size_t)EE*NH*2;

  pack_wt<<<(WC*DIN+255)/256, 256, 0, stream>>>(fc_r1, attn_l_r1, fc_r2, attn_r_r2, loopw, WtU);
  pack_wt<<<(WC*DIN+255)/256, 256, 0, stream>>>(fc_r2, attn_l_r2, fc_r1, attn_r_r1, loopw, WtI);

  bhist_k<<<NBLK, 256, 0, stream>>>(dst_r1, dst_r2, bhist);
  btot_k<<<2, 256, 0, stream>>>(bhist, bktb, offs);
  bscan_k<<<2*NB, 256, 0, stream>>>(bktb, bhist);
  bscat_k<<<NBLK, 256, 0, stream>>>(src_r1, dst_r1, src_r2, dst_r2, bhist, binned);
  fine_k<<<dim3(NB,2), 256, 0, stream>>>(binned, bktb, offs, sorted1, sorted2);

  gemm_mfma<<<(NU+127)/128, 512, 0, stream>>>(feat_user, WtU, hsbU, loopbU, scU, NU);
  gemm_mfma<<<(NI+127)/128, 512, 0, stream>>>(feat_item, WtI, hsbI, loopbI, scI, NI);

  weight_k<<<(2*NN*64 + 255)/256, 256, 0, stream>>>(scU, scI, offs, sorted1, sorted2, w1, w2);
  agg_k<<<(2*NN*64 + 255)/256, 256, 0, stream>>>(hsbU, hsbI, loopbU, loopbI, w1, w2,
                                                 offs, sorted1, sorted2, out);
}